// Round 1
// baseline (316.343 us; speedup 1.0000x reference)
//
#include <hip/hip_runtime.h>

// ---------------------------------------------------------------------------
// Compile-time Wigner 3j (exact 1:1 port of the reference Python, fp64)
// ---------------------------------------------------------------------------
struct CD { double re, im; };
constexpr CD cmul(CD a, CD b){ return CD{a.re*b.re - a.im*b.im, a.re*b.im + a.im*b.re}; }
constexpr CD conj_(CD a){ return CD{a.re, -a.im}; }

constexpr double factd(int n){ double r = 1.0; for(int i = 2; i <= n; ++i) r *= (double)i; return r; }
constexpr double csqrt_(double x){
  if (x <= 0.0) return 0.0;
  double g = x > 1.0 ? x : 1.0;
  for (int i = 0; i < 100; ++i) g = 0.5*(g + x/g);
  return g;
}

constexpr double su2_cg(int j1,int m1,int j2,int m2,int j3,int m3){
  if (m3 != m1 + m2) return 0.0;
  int vmin = -j1 + j2 + m3;
  if (-j1 + m1 > vmin) vmin = -j1 + m1;
  if (0 > vmin) vmin = 0;
  int vmax = j2 + j3 + m1;
  if (j3 - j1 + j2 < vmax) vmax = j3 - j1 + j2;
  if (j3 + m3 < vmax) vmax = j3 + m3;
  double c = csqrt_((2.0*j3 + 1.0) * factd(j3 + j1 - j2) * factd(j3 - j1 + j2) * factd(j1 + j2 - j3)
                    * factd(j3 + m3) * factd(j3 - m3)
                    / (factd(j1 + j2 + j3 + 1) * factd(j1 - m1) * factd(j1 + m1)
                       * factd(j2 - m2) * factd(j2 + m2)));
  double s = 0.0;
  for (int v = vmin; v <= vmax; ++v){
    double t = (((v + j2 + m2) & 1) ? -1.0 : 1.0) / factd(v)
               * factd(j2 + j3 + m1 - v) * factd(j1 - m1 + v)
               / factd(j3 - j1 + j2 - v) / factd(j3 + m3 - v) / factd(v + j1 - j2 - m3);
    s += t;
  }
  return c * s;
}

struct QM { CD m[7][7]; };
constexpr QM qmat(int l){
  QM q{};
  double is2 = 1.0 / csqrt_(2.0);
  for (int mm = -l; mm < 0; ++mm){
    q.m[l+mm][l-mm] = CD{is2, 0.0};     // q[l+m, l+|m|] = 1/sqrt2
    q.m[l+mm][l+mm] = CD{0.0, -is2};    // q[l+m, l-|m|] = -i/sqrt2
  }
  q.m[l][l] = CD{1.0, 0.0};
  for (int mm = 1; mm <= l; ++mm){
    double sgn = (mm & 1) ? -1.0 : 1.0;
    q.m[l+mm][l+mm] = CD{sgn*is2, 0.0};
    q.m[l+mm][l-mm] = CD{0.0, sgn*is2};
  }
  // multiply by (-i)^l
  CD ph = (l % 4 == 0) ? CD{1,0} : (l % 4 == 1) ? CD{0,-1} : (l % 4 == 2) ? CD{-1,0} : CD{0,1};
  for (int r = 0; r < 7; ++r)
    for (int c = 0; c < 7; ++c)
      q.m[r][c] = cmul(ph, q.m[r][c]);
  return q;
}

template<int L1,int L2,int L3> struct W3JT { float v[2*L1+1][2*L2+1][2*L3+1]; };

template<int L1,int L2,int L3>
constexpr W3JT<L1,L2,L3> make_w3j(){
  constexpr int D1 = 2*L1+1, D2 = 2*L2+1, D3 = 2*L3+1;
  QM q1 = qmat(L1), q2 = qmat(L2), q3 = qmat(L3);
  double cg[7][7] = {};
  for (int i = 0; i < D1; ++i)
    for (int k = 0; k < D2; ++k){
      int n = i + k - L1 - L2 + L3;   // m3 = m1 + m2
      if (n >= 0 && n < D3) cg[i][k] = su2_cg(L1, i-L1, L2, k-L2, L3, (i-L1)+(k-L2));
    }
  double c[D1][D2][D3] = {};
  double norm2 = 0.0;
  for (int j = 0; j < D1; ++j)
    for (int l = 0; l < D2; ++l)
      for (int m = 0; m < D3; ++m){
        CD s{0.0, 0.0};
        for (int i = 0; i < D1; ++i)
          for (int k = 0; k < D2; ++k){
            double g = cg[i][k];
            if (g == 0.0) continue;
            int n = i + k - L1 - L2 + L3;
            CD t = cmul(q1.m[i][j], q2.m[k][l]);
            t = cmul(t, conj_(q3.m[n][m]));
            s.re += t.re * g; s.im += t.im * g;
          }
        c[j][l][m] = s.re;
        norm2 += s.re * s.re;
      }
  double inv = 1.0 / csqrt_(norm2);
  W3JT<L1,L2,L3> w{};
  for (int j = 0; j < D1; ++j)
    for (int l = 0; l < D2; ++l)
      for (int m = 0; m < D3; ++m){
        double val = c[j][l][m] * inv;
        if (val < 1e-10 && val > -1e-10) val = 0.0;   // clean structural zeros
        w.v[j][l][m] = (float)val;
      }
  return w;
}

// per-path coefficient: sqrt((2*l3+1) / (N_TO[l3] * 64 * 64))
constexpr double NTO_[4] = {4.0, 6.0, 7.0, 6.0};
template<int L3> constexpr float path_coeff(){ return (float)csqrt_((2.0*L3+1.0)/(NTO_[L3]*4096.0)); }

// ---------------------------------------------------------------------------
// Types
// ---------------------------------------------------------------------------
typedef __bf16 bf16x8 __attribute__((ext_vector_type(8)));
typedef float  f32x4  __attribute__((ext_vector_type(4)));

// ---------------------------------------------------------------------------
// Prep: pack weights fp32 -> bf16 in MFMA B-fragment order
// layout: idx = ((((p*64+u)*2+vc)*4+nt)*64+lane)*8 + e
//   packs W[p][u][ v = vc*32 + (lane>>4)*8 + e ][ w = nt*16 + (lane&15) ]
// ---------------------------------------------------------------------------
__global__ void pack_w_kernel(const float* __restrict__ w, unsigned short* __restrict__ wp, int total){
  int idx = blockIdx.x * 256 + threadIdx.x;
  if (idx >= total) return;
  int e    = idx & 7;
  int lane = (idx >> 3) & 63;
  int nt   = (idx >> 9) & 3;
  int vc   = (idx >> 11) & 1;
  int u    = (idx >> 12) & 63;
  int p    = idx >> 18;
  int v  = vc*32 + (lane >> 4)*8 + e;
  int wc = nt*16 + (lane & 15);
  float val = w[(((size_t)p*64 + u)*64 + v)*64 + wc];
  unsigned bits = __builtin_bit_cast(unsigned, val);
  unsigned r = (bits + 0x7FFFu + ((bits >> 16) & 1u)) >> 16;   // RNE
  wp[idx] = (unsigned short)r;
}

// ---------------------------------------------------------------------------
// Main: one k3-group pass (acc regs bounded by G<=4)
// wave wv covers v-half [wv*32, wv*32+32); 16-z tile per block.
// ---------------------------------------------------------------------------
template<int P,int L1,int L2,int L3,int G0,int G>
__device__ __forceinline__ void run_group(
    int tile, int lane, int wv,
    const float (&x2r)[8][2*L2+1],
    const float* __restrict__ x1p,
    const unsigned short* __restrict__ wbase,
    float* __restrict__ out, float* red)
{
  constexpr int D1 = 2*L1+1, D2 = 2*L2+1, K3 = 2*L3+1;
  constexpr auto C = make_w3j<L1,L2,L3>();

  f32x4 acc[G][4];
  #pragma unroll
  for (int a = 0; a < G; ++a)
    #pragma unroll
    for (int b = 0; b < 4; ++b) acc[a][b] = f32x4{0.f,0.f,0.f,0.f};

  for (int u = 0; u < 64; ++u){
    bf16x8 bfrag[4];
    const unsigned short* wu = wbase + (size_t)u*4096;
    #pragma unroll
    for (int nt = 0; nt < 4; ++nt)
      bfrag[nt] = *reinterpret_cast<const bf16x8*>(wu + nt*512);

    float x1r[D1];
    #pragma unroll
    for (int i = 0; i < D1; ++i) x1r[i] = x1p[u*D1 + i];

    #pragma unroll
    for (int kk = 0; kk < G; ++kk){
      float dk[D2];
      #pragma unroll
      for (int j = 0; j < D2; ++j) dk[j] = 0.f;
      #pragma unroll
      for (int i = 0; i < D1; ++i){
        #pragma unroll
        for (int j = 0; j < D2; ++j){
          const float cv = C.v[i][j][G0+kk];     // compile-time constant
          if (cv != 0.0f) dk[j] = __builtin_fmaf(x1r[i], cv, dk[j]);
        }
      }
      bf16x8 af;
      #pragma unroll
      for (int e = 0; e < 8; ++e){
        float t = 0.f;
        #pragma unroll
        for (int j = 0; j < D2; ++j) t = __builtin_fmaf(x2r[e][j], dk[j], t);
        af[e] = (__bf16)t;
      }
      #pragma unroll
      for (int nt = 0; nt < 4; ++nt)
        acc[kk][nt] = __builtin_amdgcn_mfma_f32_16x16x32_bf16(af, bfrag[nt], acc[kk][nt], 0, 0, 0);
    }
  }

  // combine the two K-halves via LDS, then atomically accumulate into out
  __syncthreads();
  if (wv == 1){
    #pragma unroll
    for (int kk = 0; kk < G; ++kk)
      #pragma unroll
      for (int nt = 0; nt < 4; ++nt)
        *reinterpret_cast<f32x4*>(&red[((kk*4 + nt)*64 + lane)*4]) = acc[kk][nt];
  }
  __syncthreads();
  if (wv == 0){
    constexpr float CO = path_coeff<L3>();
    #pragma unroll
    for (int kk = 0; kk < G; ++kk)
      #pragma unroll
      for (int nt = 0; nt < 4; ++nt){
        f32x4 o = *reinterpret_cast<const f32x4*>(&red[((kk*4 + nt)*64 + lane)*4]);
        #pragma unroll
        for (int r = 0; r < 4; ++r){
          int zl = ((lane >> 4) << 2) + r;            // D row = (lane>>4)*4 + reg
          int wc = nt*16 + (lane & 15);               // D col = lane&15
          float val = (acc[kk][nt][r] + o[r]) * CO;
          unsafeAtomicAdd(out + (size_t)(tile*16 + zl)*1024 + 64*L3*L3 + wc*K3 + (G0+kk), val);
        }
      }
  }
  __syncthreads();
}

template<int P,int L1,int L2,int L3>
__device__ __forceinline__ void run_path(int tile, const float* __restrict__ x,
    const unsigned short* __restrict__ wp, float* __restrict__ out, float* red)
{
  constexpr int D2 = 2*L2+1, K3 = 2*L3+1;
  const int lane = threadIdx.x & 63;
  const int wv   = threadIdx.x >> 6;                 // 0/1 = v-half
  const int z    = tile*16 + (lane & 15);            // A row = lane&15
  const float* xz = x + (size_t)z*1024;

  float x2r[8][D2];
  const float* x2p = xz + 64*L2*L2 + (size_t)(wv*32 + (lane >> 4)*8)*D2;
  #pragma unroll
  for (int e = 0; e < 8; ++e)
    #pragma unroll
    for (int j = 0; j < D2; ++j) x2r[e][j] = x2p[e*D2 + j];

  const float* x1p = xz + 64*L1*L1;
  const unsigned short* wbase = wp + (size_t)P*64*4096 + (size_t)wv*2048 + (size_t)lane*8;

  if constexpr (K3 <= 4) {
    run_group<P,L1,L2,L3,0,K3>(tile, lane, wv, x2r, x1p, wbase, out, red);
  } else {
    run_group<P,L1,L2,L3,0,4>(tile, lane, wv, x2r, x1p, wbase, out, red);
    run_group<P,L1,L2,L3,4,K3-4>(tile, lane, wv, x2r, x1p, wbase, out, red);
  }
}

// heavy-first dispatch: slot -> original path index P and (l1,l2,l3)
__global__ __launch_bounds__(128, 2) void tp_main(const float* __restrict__ x,
    const unsigned short* __restrict__ wp, float* __restrict__ out)
{
  __shared__ __align__(16) float red[4096];
  const int slot = blockIdx.x >> 7;
  const int tile = blockIdx.x & 127;
  switch (slot){
    case 0:  run_path< 3,0,3,3>(tile,x,wp,out,red); break;
    case 1:  run_path<16,2,3,3>(tile,x,wp,out,red); break;
    case 2:  run_path< 8,1,2,3>(tile,x,wp,out,red); break;
    case 3:  run_path< 9,1,3,2>(tile,x,wp,out,red); break;
    case 4:  run_path<20,3,2,3>(tile,x,wp,out,red); break;
    case 5:  run_path<22,3,3,2>(tile,x,wp,out,red); break;
    case 6:  run_path< 2,0,2,2>(tile,x,wp,out,red); break;
    case 7:  run_path<14,2,2,2>(tile,x,wp,out,red); break;
    case 8:  run_path<12,2,1,3>(tile,x,wp,out,red); break;
    case 9:  run_path<15,2,3,1>(tile,x,wp,out,red); break;
    case 10: run_path< 6,1,1,2>(tile,x,wp,out,red); break;
    case 11: run_path< 7,1,2,1>(tile,x,wp,out,red); break;
    case 12: run_path<18,3,1,2>(tile,x,wp,out,red); break;
    case 13: run_path<19,3,2,1>(tile,x,wp,out,red); break;
    case 14: run_path< 1,0,1,1>(tile,x,wp,out,red); break;
    case 15: run_path<11,2,1,1>(tile,x,wp,out,red); break;
    case 16: run_path<17,3,0,3>(tile,x,wp,out,red); break;
    case 17: run_path<21,3,3,0>(tile,x,wp,out,red); break;
    case 18: run_path<10,2,0,2>(tile,x,wp,out,red); break;
    case 19: run_path<13,2,2,0>(tile,x,wp,out,red); break;
    case 20: run_path< 4,1,0,1>(tile,x,wp,out,red); break;
    case 21: run_path< 5,1,1,0>(tile,x,wp,out,red); break;
    case 22: run_path< 0,0,0,0>(tile,x,wp,out,red); break;
    default: break;
  }
}

// ---------------------------------------------------------------------------
extern "C" void kernel_launch(void* const* d_in, const int* in_sizes, int n_in,
                              void* d_out, int out_size, void* d_ws, size_t ws_size,
                              hipStream_t stream)
{
  const float* x = (const float*)d_in[0];        // [2,1024,1024] fp32
  const float* w = (const float*)d_in[1];        // [23,64,64,64] fp32
  float* out = (float*)d_out;                    // [2,1024,1024] fp32
  unsigned short* wp = (unsigned short*)d_ws;

  const int total = 23*64*2*4*64*8;              // 6,029,312 packed bf16 elems
  if (ws_size < (size_t)total * sizeof(unsigned short)) return;  // need ~12.1 MB scratch

  hipMemsetAsync(d_out, 0, (size_t)out_size * sizeof(float), stream);
  pack_w_kernel<<<(total + 255)/256, 256, 0, stream>>>(w, wp, total);
  tp_main<<<23*128, 128, 0, stream>>>(x, wp, out);
}

// Round 2
// 225.827 us; speedup vs baseline: 1.4008x; 1.4008x over previous
//
#include <hip/hip_runtime.h>

// ---------------------------------------------------------------------------
// Compile-time Wigner 3j (exact port of the reference Python, fp64)
// ---------------------------------------------------------------------------
struct CD { double re, im; };
constexpr CD cmul(CD a, CD b){ return CD{a.re*b.re - a.im*b.im, a.re*b.im + a.im*b.re}; }
constexpr CD conj_(CD a){ return CD{a.re, -a.im}; }

constexpr double factd(int n){ double r = 1.0; for(int i = 2; i <= n; ++i) r *= (double)i; return r; }
constexpr double csqrt_(double x){
  if (x <= 0.0) return 0.0;
  double g = x > 1.0 ? x : 1.0;
  for (int i = 0; i < 100; ++i) g = 0.5*(g + x/g);
  return g;
}

constexpr double su2_cg(int j1,int m1,int j2,int m2,int j3,int m3){
  if (m3 != m1 + m2) return 0.0;
  int vmin = -j1 + j2 + m3;
  if (-j1 + m1 > vmin) vmin = -j1 + m1;
  if (0 > vmin) vmin = 0;
  int vmax = j2 + j3 + m1;
  if (j3 - j1 + j2 < vmax) vmax = j3 - j1 + j2;
  if (j3 + m3 < vmax) vmax = j3 + m3;
  double c = csqrt_((2.0*j3 + 1.0) * factd(j3 + j1 - j2) * factd(j3 - j1 + j2) * factd(j1 + j2 - j3)
                    * factd(j3 + m3) * factd(j3 - m3)
                    / (factd(j1 + j2 + j3 + 1) * factd(j1 - m1) * factd(j1 + m1)
                       * factd(j2 - m2) * factd(j2 + m2)));
  double s = 0.0;
  for (int v = vmin; v <= vmax; ++v){
    double t = (((v + j2 + m2) & 1) ? -1.0 : 1.0) / factd(v)
               * factd(j2 + j3 + m1 - v) * factd(j1 - m1 + v)
               / factd(j3 - j1 + j2 - v) / factd(j3 + m3 - v) / factd(v + j1 - j2 - m3);
    s += t;
  }
  return c * s;
}

struct QM { CD m[7][7]; };
constexpr QM qmat(int l){
  QM q{};
  double is2 = 1.0 / csqrt_(2.0);
  for (int mm = -l; mm < 0; ++mm){
    q.m[l+mm][l-mm] = CD{is2, 0.0};
    q.m[l+mm][l+mm] = CD{0.0, -is2};
  }
  q.m[l][l] = CD{1.0, 0.0};
  for (int mm = 1; mm <= l; ++mm){
    double sgn = (mm & 1) ? -1.0 : 1.0;
    q.m[l+mm][l+mm] = CD{sgn*is2, 0.0};
    q.m[l+mm][l-mm] = CD{0.0, sgn*is2};
  }
  CD ph = (l % 4 == 0) ? CD{1,0} : (l % 4 == 1) ? CD{0,-1} : (l % 4 == 2) ? CD{-1,0} : CD{0,1};
  for (int r = 0; r < 7; ++r)
    for (int c = 0; c < 7; ++c)
      q.m[r][c] = cmul(ph, q.m[r][c]);
  return q;
}

template<int L1,int L2,int L3> struct W3JT { float v[2*L1+1][2*L2+1][2*L3+1]; };

template<int L1,int L2,int L3>
constexpr W3JT<L1,L2,L3> make_w3j(){
  constexpr int D1 = 2*L1+1, D2 = 2*L2+1, D3 = 2*L3+1;
  QM q1 = qmat(L1), q2 = qmat(L2), q3 = qmat(L3);
  double cg[7][7] = {};
  for (int i = 0; i < D1; ++i)
    for (int k = 0; k < D2; ++k){
      int n = i + k - L1 - L2 + L3;
      if (n >= 0 && n < D3) cg[i][k] = su2_cg(L1, i-L1, L2, k-L2, L3, (i-L1)+(k-L2));
    }
  double c[D1][D2][D3] = {};
  double norm2 = 0.0;
  for (int j = 0; j < D1; ++j)
    for (int l = 0; l < D2; ++l)
      for (int m = 0; m < D3; ++m){
        CD s{0.0, 0.0};
        for (int i = 0; i < D1; ++i)
          for (int k = 0; k < D2; ++k){
            double g = cg[i][k];
            if (g == 0.0) continue;
            int n = i + k - L1 - L2 + L3;
            CD t = cmul(q1.m[i][j], q2.m[k][l]);
            t = cmul(t, conj_(q3.m[n][m]));
            s.re += t.re * g; s.im += t.im * g;
          }
        c[j][l][m] = s.re;
        norm2 += s.re * s.re;
      }
  double inv = 1.0 / csqrt_(norm2);
  W3JT<L1,L2,L3> w{};
  for (int j = 0; j < D1; ++j)
    for (int l = 0; l < D2; ++l)
      for (int m = 0; m < D3; ++m){
        double val = c[j][l][m] * inv;
        if (val < 1e-10 && val > -1e-10) val = 0.0;
        w.v[j][l][m] = (float)val;
      }
  return w;
}

// ---------------------------------------------------------------------------
// Path tables (lexicographic e3nn order)
// ---------------------------------------------------------------------------
__device__ __constant__ int L3P_[23] = {0,1,2,3,1,0,2,1,3,2,2,1,3,0,2,1,3,3,2,1,3,0,2};
// cumulative K3 (2*l3+1) before each path; [23] = 99
constexpr int K3CUM[24] = {0,1,4,9,16,19,20,25,28,35,40,45,48,55,56,61,64,71,78,83,86,93,94,99};
constexpr size_t ZW = 2048ull * 64ull;   // 131072 elements per unit of K3

typedef __bf16 bf16x8 __attribute__((ext_vector_type(8)));
typedef float  f32x4  __attribute__((ext_vector_type(4)));

// ---------------------------------------------------------------------------
// Prep 1: pack weights fp32 -> bf16 (coeff folded in), MFMA B-fragment order
// idx = ((((p*64+u)*2+vc)*4+nt)*64+lane)*8 + e
//   packs W[p][u][ v = vc*32 + (lane>>4)*8 + e ][ w = nt*16 + (lane&15) ]
// ---------------------------------------------------------------------------
__global__ void pack_w_kernel(const float* __restrict__ w, unsigned short* __restrict__ wp, int total){
  int idx = blockIdx.x * 256 + threadIdx.x;
  if (idx >= total) return;
  int e    = idx & 7;
  int lane = (idx >> 3) & 63;
  int nt   = (idx >> 9) & 3;
  int vc   = (idx >> 11) & 1;
  int u    = (idx >> 12) & 63;
  int p    = idx >> 18;
  int v  = vc*32 + (lane >> 4)*8 + e;
  int wc = nt*16 + (lane & 15);
  int l3 = L3P_[p];
  const float nto[4] = {4.f, 6.f, 7.f, 6.f};
  float coeff = sqrtf((2.f*l3 + 1.f) / (nto[l3] * 4096.f));
  float val = w[(((size_t)p*64 + u)*64 + v)*64 + wc] * coeff;
  unsigned bits = __builtin_bit_cast(unsigned, val);
  unsigned r = (bits + 0x7FFFu + ((bits >> 16) & 1u)) >> 16;   // RNE
  wp[idx] = (unsigned short)r;
}

// ---------------------------------------------------------------------------
// Prep 2: transpose x [2048][1024] -> xT [1024][2048] for coalesced lane reads
// ---------------------------------------------------------------------------
__global__ void transpose_x(const float* __restrict__ x, float* __restrict__ xT){
  __shared__ float t[32][33];
  int bx = blockIdx.x;            // d-tile (32 of them)
  int by = blockIdx.y;            // z-tile (64 of them)
  int tx = threadIdx.x & 31, ty = threadIdx.x >> 5;   // 32x8
  #pragma unroll
  for (int r = 0; r < 4; ++r)
    t[ty + r*8][tx] = x[(size_t)(by*32 + ty + r*8)*1024 + bx*32 + tx];
  __syncthreads();
  #pragma unroll
  for (int r = 0; r < 4; ++r)
    xT[(size_t)(bx*32 + ty + r*8)*2048 + by*32 + tx] = t[tx][ty + r*8];
}

// ---------------------------------------------------------------------------
// Main: one (path, k3-chunk) slot per block. 16-z tile, 2 waves = v-halves.
// PART=true: store partials to ws (gather sums per-l3 paths).
// PART=false: unsafeAtomicAdd directly into out.
// ---------------------------------------------------------------------------
template<int P,int L1,int L2,int L3,int G0,int G,bool PART>
__device__ __forceinline__ void run_slot(
    int tile, const float* __restrict__ xT,
    const unsigned short* __restrict__ wp,
    float* __restrict__ dst, float* red)
{
  constexpr int D1 = 2*L1+1, D2 = 2*L2+1, K3 = 2*L3+1;
  constexpr auto C = make_w3j<L1,L2,L3>();

  const int lane = threadIdx.x & 63;
  const int wv   = threadIdx.x >> 6;                // v-half 0/1
  const int zc   = tile*16 + (lane & 15);           // this lane's z (A row)

  // x2 fragment: 8 v-values x D2, coalesced via xT
  float x2r[8][D2];
  {
    const float* x2b = xT + (size_t)(64*L2*L2)*2048 + zc;
    const int v0 = wv*32 + (lane >> 4)*8;
    #pragma unroll
    for (int e = 0; e < 8; ++e)
      #pragma unroll
      for (int j = 0; j < D2; ++j)
        x2r[e][j] = x2b[(size_t)((v0 + e)*D2 + j)*2048];
  }

  const float* x1b = xT + (size_t)(64*L1*L1)*2048 + zc;
  const unsigned short* wbase = wp + (size_t)P*262144 + (size_t)wv*2048 + (size_t)lane*8;

  f32x4 acc[G][4];
  #pragma unroll
  for (int a = 0; a < G; ++a)
    #pragma unroll
    for (int b = 0; b < 4; ++b) acc[a][b] = f32x4{0.f,0.f,0.f,0.f};

  for (int u = 0; u < 64; ++u){
    bf16x8 bfrag[4];
    const unsigned short* wu = wbase + (size_t)u*4096;
    #pragma unroll
    for (int nt = 0; nt < 4; ++nt)
      bfrag[nt] = *reinterpret_cast<const bf16x8*>(wu + nt*512);

    float x1r[D1];
    #pragma unroll
    for (int i = 0; i < D1; ++i) x1r[i] = x1b[(size_t)(u*D1 + i)*2048];

    #pragma unroll
    for (int kk = 0; kk < G; ++kk){
      float dk[D2];
      #pragma unroll
      for (int j = 0; j < D2; ++j) dk[j] = 0.f;
      #pragma unroll
      for (int i = 0; i < D1; ++i){
        #pragma unroll
        for (int j = 0; j < D2; ++j){
          const float cv = C.v[i][j][G0+kk];
          if (cv != 0.0f) dk[j] = __builtin_fmaf(x1r[i], cv, dk[j]);
        }
      }
      bf16x8 af;
      #pragma unroll
      for (int e = 0; e < 8; ++e){
        float t = 0.f;
        #pragma unroll
        for (int j = 0; j < D2; ++j) t = __builtin_fmaf(x2r[e][j], dk[j], t);
        af[e] = (__bf16)t;
      }
      #pragma unroll
      for (int nt = 0; nt < 4; ++nt)
        acc[kk][nt] = __builtin_amdgcn_mfma_f32_16x16x32_bf16(af, bfrag[nt], acc[kk][nt], 0, 0, 0);
    }
  }

  // combine v-halves via LDS (one barrier), wave0 stores
  if (wv == 1){
    #pragma unroll
    for (int kk = 0; kk < G; ++kk)
      #pragma unroll
      for (int nt = 0; nt < 4; ++nt)
        *reinterpret_cast<f32x4*>(&red[((kk*4 + nt)*64 + lane)*4]) = acc[kk][nt];
  }
  __syncthreads();
  if (wv == 0){
    #pragma unroll
    for (int kk = 0; kk < G; ++kk)
      #pragma unroll
      for (int nt = 0; nt < 4; ++nt){
        f32x4 o = *reinterpret_cast<const f32x4*>(&red[((kk*4 + nt)*64 + lane)*4]);
        #pragma unroll
        for (int r = 0; r < 4; ++r){
          int zl = ((lane >> 4) << 2) + r;           // D row
          int wc = nt*16 + (lane & 15);              // D col
          float val = acc[kk][nt][r] + o[r];
          if constexpr (PART){
            dst[(size_t)K3CUM[P]*ZW + (size_t)(tile*16 + zl)*(64*K3) + wc*K3 + (G0+kk)] = val;
          } else {
            unsafeAtomicAdd(dst + (size_t)(tile*16 + zl)*1024 + 64*L3*L3 + wc*K3 + (G0+kk), val);
          }
        }
      }
  }
}

template<bool PART>
__global__ __launch_bounds__(128, 3) void tp_main(const float* __restrict__ xT,
    const unsigned short* __restrict__ wp, float* __restrict__ dst)
{
  __shared__ __align__(16) float red[4096];
  const int slot = blockIdx.x >> 7;
  const int tile = blockIdx.x & 127;
  switch (slot){
    // heavy-first (approx. VALU work descending)
    case 0:  run_slot< 3,0,3,3,0,4,PART>(tile,xT,wp,dst,red); break;
    case 1:  run_slot<16,2,3,3,0,4,PART>(tile,xT,wp,dst,red); break;
    case 2:  run_slot< 9,1,3,2,0,4,PART>(tile,xT,wp,dst,red); break;
    case 3:  run_slot<22,3,3,2,0,4,PART>(tile,xT,wp,dst,red); break;
    case 4:  run_slot< 8,1,2,3,0,4,PART>(tile,xT,wp,dst,red); break;
    case 5:  run_slot<20,3,2,3,0,4,PART>(tile,xT,wp,dst,red); break;
    case 6:  run_slot< 2,0,2,2,0,4,PART>(tile,xT,wp,dst,red); break;
    case 7:  run_slot<14,2,2,2,0,4,PART>(tile,xT,wp,dst,red); break;
    case 8:  run_slot< 3,0,3,3,4,3,PART>(tile,xT,wp,dst,red); break;
    case 9:  run_slot<16,2,3,3,4,3,PART>(tile,xT,wp,dst,red); break;
    case 10: run_slot<15,2,3,1,0,3,PART>(tile,xT,wp,dst,red); break;
    case 11: run_slot< 8,1,2,3,4,3,PART>(tile,xT,wp,dst,red); break;
    case 12: run_slot<20,3,2,3,4,3,PART>(tile,xT,wp,dst,red); break;
    case 13: run_slot< 7,1,2,1,0,3,PART>(tile,xT,wp,dst,red); break;
    case 14: run_slot<19,3,2,1,0,3,PART>(tile,xT,wp,dst,red); break;
    case 15: run_slot<18,3,1,2,0,4,PART>(tile,xT,wp,dst,red); break;
    case 16: run_slot< 6,1,1,2,0,4,PART>(tile,xT,wp,dst,red); break;
    case 17: run_slot<12,2,1,3,0,4,PART>(tile,xT,wp,dst,red); break;
    case 18: run_slot<12,2,1,3,4,3,PART>(tile,xT,wp,dst,red); break;
    case 19: run_slot< 1,0,1,1,0,3,PART>(tile,xT,wp,dst,red); break;
    case 20: run_slot<11,2,1,1,0,3,PART>(tile,xT,wp,dst,red); break;
    case 21: run_slot<17,3,0,3,0,4,PART>(tile,xT,wp,dst,red); break;
    case 22: run_slot<10,2,0,2,0,4,PART>(tile,xT,wp,dst,red); break;
    case 23: run_slot< 9,1,3,2,4,1,PART>(tile,xT,wp,dst,red); break;
    case 24: run_slot<22,3,3,2,4,1,PART>(tile,xT,wp,dst,red); break;
    case 25: run_slot<21,3,3,0,0,1,PART>(tile,xT,wp,dst,red); break;
    case 26: run_slot<17,3,0,3,4,3,PART>(tile,xT,wp,dst,red); break;
    case 27: run_slot< 4,1,0,1,0,3,PART>(tile,xT,wp,dst,red); break;
    case 28: run_slot< 2,0,2,2,4,1,PART>(tile,xT,wp,dst,red); break;
    case 29: run_slot<14,2,2,2,4,1,PART>(tile,xT,wp,dst,red); break;
    case 30: run_slot<13,2,2,0,0,1,PART>(tile,xT,wp,dst,red); break;
    case 31: run_slot< 6,1,1,2,4,1,PART>(tile,xT,wp,dst,red); break;
    case 32: run_slot<18,3,1,2,4,1,PART>(tile,xT,wp,dst,red); break;
    case 33: run_slot< 5,1,1,0,0,1,PART>(tile,xT,wp,dst,red); break;
    case 34: run_slot<10,2,0,2,4,1,PART>(tile,xT,wp,dst,red); break;
    case 35: run_slot< 0,0,0,0,0,1,PART>(tile,xT,wp,dst,red); break;
    default: break;
  }
}

// ---------------------------------------------------------------------------
// Gather: out[z][seg] = sum of per-path partials (coeff already folded in)
// partial layout per path: [z][w*K3 + k], identical to the out segment layout
// ---------------------------------------------------------------------------
__global__ void gather_out(const float* __restrict__ part, float* __restrict__ out){
  int gid = blockIdx.x * 256 + threadIdx.x;
  int z = gid >> 10, j = gid & 1023;
  float s;
  if (j < 64){                               // l3=0, K3=1, paths {0,5,13,21}
    size_t b = (size_t)z*64 + j;
    s = part[(size_t)K3CUM[0]*ZW + b] + part[(size_t)K3CUM[5]*ZW + b]
      + part[(size_t)K3CUM[13]*ZW + b] + part[(size_t)K3CUM[21]*ZW + b];
  } else if (j < 256){                       // l3=1, K3=3, paths {1,4,7,11,15,19}
    size_t b = (size_t)z*192 + (j - 64);
    s = part[(size_t)K3CUM[1]*ZW + b] + part[(size_t)K3CUM[4]*ZW + b]
      + part[(size_t)K3CUM[7]*ZW + b] + part[(size_t)K3CUM[11]*ZW + b]
      + part[(size_t)K3CUM[15]*ZW + b] + part[(size_t)K3CUM[19]*ZW + b];
  } else if (j < 576){                       // l3=2, K3=5, paths {2,6,9,10,14,18,22}
    size_t b = (size_t)z*320 + (j - 256);
    s = part[(size_t)K3CUM[2]*ZW + b] + part[(size_t)K3CUM[6]*ZW + b]
      + part[(size_t)K3CUM[9]*ZW + b] + part[(size_t)K3CUM[10]*ZW + b]
      + part[(size_t)K3CUM[14]*ZW + b] + part[(size_t)K3CUM[18]*ZW + b]
      + part[(size_t)K3CUM[22]*ZW + b];
  } else {                                   // l3=3, K3=7, paths {3,8,12,16,17,20}
    size_t b = (size_t)z*448 + (j - 576);
    s = part[(size_t)K3CUM[3]*ZW + b] + part[(size_t)K3CUM[8]*ZW + b]
      + part[(size_t)K3CUM[12]*ZW + b] + part[(size_t)K3CUM[16]*ZW + b]
      + part[(size_t)K3CUM[17]*ZW + b] + part[(size_t)K3CUM[20]*ZW + b];
  }
  out[gid] = s;
}

// ---------------------------------------------------------------------------
extern "C" void kernel_launch(void* const* d_in, const int* in_sizes, int n_in,
                              void* d_out, int out_size, void* d_ws, size_t ws_size,
                              hipStream_t stream)
{
  const float* x = (const float*)d_in[0];        // [2,1024,1024] fp32
  const float* w = (const float*)d_in[1];        // [23,64,64,64] fp32
  float* out = (float*)d_out;                    // [2,1024,1024] fp32

  const size_t packB = 23ull*64*2*4*64*8 * sizeof(unsigned short);   // 12,058,624
  const size_t xTB   = 1024ull*2048*sizeof(float);                   //  8,388,608
  const size_t partB = 99ull*ZW*sizeof(float);                       // 51,904,512
  const int totalW = 23*64*2*4*64*8;

  unsigned short* wp = (unsigned short*)d_ws;
  float* xT   = (float*)((char*)d_ws + packB);
  float* part = (float*)((char*)d_ws + packB + xTB);

  if (ws_size < packB + xTB) return;   // cannot run at all

  pack_w_kernel<<<(totalW + 255)/256, 256, 0, stream>>>(w, wp, totalW);
  dim3 tg(32, 64);
  transpose_x<<<tg, 256, 0, stream>>>(x, xT);

  if (ws_size >= packB + xTB + partB){
    tp_main<true><<<36*128, 128, 0, stream>>>(xT, wp, part);
    gather_out<<<(2048*1024)/256, 256, 0, stream>>>(part, out);
  } else {
    hipMemsetAsync(d_out, 0, (size_t)out_size * sizeof(float), stream);
    tp_main<false><<<36*128, 128, 0, stream>>>(xT, wp, out);
  }
}